// Round 7
// baseline (125.950 us; speedup 1.0000x reference)
//
#include <hip/hip_runtime.h>
#include <hip/hip_bf16.h>

typedef __attribute__((ext_vector_type(8))) short short8;
typedef __attribute__((ext_vector_type(4))) float f32x4;

static __device__ __forceinline__ unsigned short f2bf(float f){
  union { float f; unsigned int u; } v; v.f = f;
  unsigned int r = v.u + 0x7fffu + ((v.u >> 16) & 1u);
  return (unsigned short)(r >> 16);
}

static __device__ __forceinline__ void load_lds16(const unsigned short* g, unsigned short* l){
  __builtin_amdgcn_global_load_lds(
      (const __attribute__((address_space(1))) unsigned int*)(g),
      (__attribute__((address_space(3))) unsigned int*)(l), 16, 0, 0);
}

// ---------------- kernel 1: W -> Wt bf16 [p][d][e] + bias concat (tiny) -------
__global__ void k_prep(const float* __restrict__ Wq, const float* __restrict__ Wk,
                       const float* __restrict__ Wv,
                       const float* __restrict__ bq, const float* __restrict__ bk,
                       const float* __restrict__ bv,
                       unsigned short* __restrict__ Wt, float* __restrict__ bias){
  int gid = blockIdx.x * 256 + threadIdx.x;    // 0 .. 393215
  int p = gid >> 17;
  int rem = gid & 131071;
  int d = rem >> 10, e = rem & 1023;
  const float* W = (p==0) ? Wq : ((p==1) ? Wk : Wv);
  Wt[gid] = f2bf(W[e*128 + d]);                 // Wt[p][d][e] = W[e][d]
  if (gid < 384){
    int pp = gid >> 7, dd = gid & 127;
    bias[gid] = (pp==0) ? bq[dd] : ((pp==1) ? bk[dd] : bv[dd]);
  }
}

// ---------------- kernel 2: QKV GEMM reading x f32 DIRECTLY (fused cvt) -------
// A reg-staged from x: f32 load -> f2bf -> ds_write to stride-72-padded tile
// (16B aligned, even bank spread). B via global_load_lds from Wt (unchanged).
// Double-buffered, 16 K-steps of 64. XCD-chunked block map: each XCD owns
// 16 mt-tiles x 3 p so p=1,2 re-read x rows from its private L2.
// Epilogue identical to round-6 (fused bias + swizzled bf16 stores).
//   Qsw/Ksw: [rowtile16][kc(4)][quad(4)][l16(16)][8]
//   Vsw:     [b][t64][nt(8)][kc2(2)][quad(4)][l16(16)][8]
__global__ __launch_bounds__(256) void k_gemm_qkv(
    const float* __restrict__ x, const unsigned short* __restrict__ Wt,
    const float* __restrict__ bias,
    unsigned short* __restrict__ Qsw, unsigned short* __restrict__ Ksw,
    unsigned short* __restrict__ Vsw){
  // per buffer: A 64x72 bf16 = 9216 B, B 128x64 bf16 = 16384 B -> 25600 B
  __shared__ __align__(16) char smem[51200];
  float* Lf = (float*)smem;                              // [64][128] f32 (epilogue)
  int tid = threadIdx.x;
  int bid = blockIdx.x;                // 0..383
  int xcd = bid & 7;
  int slot = bid >> 3;                 // 0..47
  int mtl = slot / 3;
  int p   = slot - mtl*3;              // 0..2
  int mt  = xcd*16 + mtl;              // 0..127
  int m0 = mt * 64;
  int w = tid >> 6, lane = tid & 63, quad = lane >> 4, l16 = lane & 15;
  int wm = (w >> 1) * 32, wn = (w & 1) * 64;
  f32x4 acc[2][4];
  #pragma unroll
  for (int i=0;i<2;i++)
    #pragma unroll
    for (int j=0;j<4;j++) acc[i][j] = (f32x4){0.f,0.f,0.f,0.f};

  // A staging: thread -> (row, 16-f32 col group)
  int arow = tid >> 2;                 // 0..63
  int acg  = tid & 3;                  // 0..3
  const float* Ax = x + (size_t)(m0 + arow)*1024 + acg*16;
  float4 av[4];

  const unsigned short* Wp = Wt + p * (128*1024);
  const unsigned short* Bg = Wp + (w*32 + (lane>>3))*1024 + (lane&7)*8;
  int boff = (w*32)*64;     // shorts; wave-uniform LDS base, HW adds lane*16B

  auto aload = [&](int k0){
    #pragma unroll
    for (int i=0;i<4;i++) av[i] = *(const float4*)(Ax + k0 + i*4);
  };
  auto astore = [&](int sel){
    unsigned short h[16];
    #pragma unroll
    for (int i=0;i<4;i++){
      h[i*4+0]=f2bf(av[i].x); h[i*4+1]=f2bf(av[i].y);
      h[i*4+2]=f2bf(av[i].z); h[i*4+3]=f2bf(av[i].w);
    }
    unsigned short* Ad = (unsigned short*)(smem + sel*25600) + arow*72 + acg*16;
    *(uint4*)(Ad)   = *(uint4*)(h);
    *(uint4*)(Ad+8) = *(uint4*)(h+8);
  };
  auto bstage = [&](int sel, int k0){
    unsigned short* Bl = (unsigned short*)(smem + sel*25600 + 9216) + boff;
    #pragma unroll
    for (int s8=0; s8<4; s8++) load_lds16(Bg + k0 + s8*8192, Bl + s8*512);
  };

  aload(0); bstage(0, 0); astore(0);
  __syncthreads();                     // tile 0 resident
  int cur = 0;
  for (int t=0; t<16; t++){
    if (t < 15){ aload((t+1)*64); bstage(cur^1, (t+1)*64); }  // prefetch
    const unsigned short* Ac = (const unsigned short*)(smem + cur*25600);
    const unsigned short* Bc = Ac + 4608;
    #pragma unroll
    for (int kk=0; kk<64; kk+=32){
      short8 af[2], bf[4];
      #pragma unroll
      for (int i=0;i<2;i++) af[i] = *(const short8*)(Ac + (wm + i*16 + l16)*72 + kk + quad*8);
      #pragma unroll
      for (int j=0;j<4;j++) bf[j] = *(const short8*)(Bc + (wn + j*16 + l16)*64 + kk + quad*8);
      #pragma unroll
      for (int i=0;i<2;i++)
        #pragma unroll
        for (int j=0;j<4;j++)
          acc[i][j] = __builtin_amdgcn_mfma_f32_16x16x32_bf16(af[i], bf[j], acc[i][j], 0,0,0);
    }
    if (t < 15) astore(cur^1);         // cvt + LDS write into next buffer
    __syncthreads();                   // drains B prefetch (vmcnt) + A ds_writes
    cur ^= 1;
  }

  const float qscale = 0.08838834764831845f;  // 1/sqrt(128)
  if (p == 2){
    // V: swizzle minor dim (jj) comes from the ROW -> acc's f32x4 axis. Direct store.
    #pragma unroll
    for (int i=0;i<2;i++)
      #pragma unroll
      for (int j=0;j<4;j++){
        int grow0 = m0 + wm + i*16 + quad*4;          // 4-aligned
        int col = wn + j*16 + l16;
        unsigned short pk[4];
        float bv_ = bias[256 + col];
        #pragma unroll
        for (int r=0;r<4;r++) pk[r] = f2bf(acc[i][j][r] + bv_);
        int bb2 = grow0 >> 11, s = grow0 & 2047;
        int t64 = s >> 6, srem = s & 63;
        int kc2 = srem >> 5, q2 = (srem >> 3) & 3, jj = srem & 7;
        int nt = col >> 4, l2 = col & 15;
        *(uint2*)(Vsw + (bb2*32+t64)*8192 + nt*1024 + kc2*512 + q2*128 + l2*8 + jj) = *(uint2*)pk;
      }
  } else {
    // Q/K: need row<->col transpose for the swizzle; roundtrip through LDS.
    #pragma unroll
    for (int i=0;i<2;i++)
      #pragma unroll
      for (int j=0;j<4;j++)
        #pragma unroll
        for (int r=0;r<4;r++)
          Lf[(wm + i*16 + quad*4 + r)*128 + wn + j*16 + l16] = acc[i][j][r];
    __syncthreads();
    unsigned short* dst = (p==0)? Qsw : Ksw;
    float scale = (p==0)? qscale : 1.0f;
    #pragma unroll
    for (int it=0; it<8; it++){
      int g = it*256 + tid;            // 0..2047 (64 rows x 32 col-groups)
      int row = g >> 5, cs = (g & 31)*4;
      f32x4 a = *(const f32x4*)(Lf + row*128 + cs);
      int grow = m0 + row;
      int rt = grow >> 4, m = grow & 15;
      int kc = cs >> 5, q2 = (cs >> 3) & 3, jj = cs & 7;
      unsigned short pk[4];
      #pragma unroll
      for (int k=0;k<4;k++) pk[k] = f2bf((a[k] + bias[p*128+cs+k])*scale);
      *(uint2*)(dst + rt*2048 + kc*512 + q2*128 + m*8 + jj) = *(uint2*)pk;
    }
  }
}

// ---------------- kernel 3: attention, one BLOCK per (b, 16-row q-block) ------
// (unchanged from round 6 -- validated at 123.8 us)
__global__ __launch_bounds__(256) void k_attn(
    const unsigned short* __restrict__ Qsw, const unsigned short* __restrict__ Ksw,
    const unsigned short* __restrict__ Vsw, float* __restrict__ out){
  __shared__ __align__(16) float Ob[4*2112];            // [w][16][132] (pad 132)
  __shared__ float Ml[4][2][16];                        // [w][{m,l}][row]
  __shared__ __align__(16) unsigned short Pw[4*1280];   // per-wave P buffer
  int x = blockIdx.x;                  // 0..511
  int b = x & 3;
  int qb = x >> 2;                     // 0..127
  int T64 = (qb >> 2) + 1;             // 64-key tiles covering keys <= qb*16+15
  int tid = threadIdx.x;
  int w = tid >> 6;
  int lane = tid & 63;
  int quad = lane >> 4, l16 = lane & 15;
  int qs = qb * 16;                    // q rows qs..qs+15; our q col = qs + l16

  short8 aq[4];
  #pragma unroll
  for (int kc=0;kc<4;kc++)
    aq[kc] = *(const short8*)(Qsw + (b*128 + qb)*2048 + kc*512 + lane*8);

  f32x4 o[8];
  #pragma unroll
  for (int i=0;i<8;i++) o[i] = (f32x4){0.f,0.f,0.f,0.f};
  float mcol = -1e30f;
  float lcol = 0.f;
  short8 ap[2];
  unsigned short* Pws = Pw + w*1280;

  const unsigned short* Kb = Ksw + b*128*2048;
  const unsigned short* Vb = Vsw + b*32*8192;

  for (int tt = w; tt < T64; tt += 4){
    int t0 = tt * 64;
    // ---- batch-load ALL 16 K fragments (single exposed latency) ----
    short8 kf[16];
    #pragma unroll
    for (int nt=0;nt<4;nt++){
      const unsigned short* Kt = Kb + ((t0>>4)+nt)*2048 + lane*8;
      #pragma unroll
      for (int kc=0;kc<4;kc++)
        kf[nt*4+kc] = *(const short8*)(Kt + kc*512);
    }
    // S^T = K @ Q^T : A = K frags (m=key), B = Q frags (n=q). C: row=key, col=q.
    f32x4 sc[4];
    #pragma unroll
    for (int nt=0;nt<4;nt++) sc[nt] = (f32x4){0.f,0.f,0.f,0.f};
    __builtin_amdgcn_s_setprio(1);
    #pragma unroll
    for (int nt=0;nt<4;nt++)
      #pragma unroll
      for (int kc=0;kc<4;kc++)
        sc[nt] = __builtin_amdgcn_mfma_f32_16x16x32_bf16(kf[nt*4+kc], aq[kc], sc[nt], 0,0,0);
    __builtin_amdgcn_s_setprio(0);
    // ---- issue ALL 16 V loads now; latency hides under softmax VALU ----
    short8 vf[16];
    const unsigned short* Vt0 = Vb + (t0>>6)*8192 + lane*8;
    #pragma unroll
    for (int nt=0;nt<8;nt++)
      #pragma unroll
      for (int kc2=0;kc2<2;kc2++)
        vf[nt*2+kc2] = *(const short8*)(Vt0 + nt*1024 + kc2*512);

    if (t0 + 63 > qs){                 // mask needed iff tile's max key > min q
      #pragma unroll
      for (int nt=0;nt<4;nt++){
        int kb_ = t0 + nt*16 + quad*4;
        #pragma unroll
        for (int r=0;r<4;r++)
          if (kb_ + r > qs + l16) sc[nt][r] = -1e30f;
      }
    }
    // in-register max over 16 keys, then 2 shuffles across quads
    float mt_ = -1e30f;
    #pragma unroll
    for (int nt=0;nt<4;nt++)
      #pragma unroll
      for (int r=0;r<4;r++) mt_ = fmaxf(mt_, sc[nt][r]);
    mt_ = fmaxf(mt_, __shfl_xor(mt_, 16));
    mt_ = fmaxf(mt_, __shfl_xor(mt_, 32));
    float mn = fmaxf(mcol, mt_);
    float al = __expf(mcol - mn);
    mcol = mn;
    float ls = 0.f;
    #pragma unroll
    for (int nt=0;nt<4;nt++)
      #pragma unroll
      for (int r=0;r<4;r++){
        float pv = __expf(sc[nt][r] - mn);
        sc[nt][r] = pv;
        ls += pv;
      }
    ls += __shfl_xor(ls, 16);
    ls += __shfl_xor(ls, 32);
    lcol = lcol*al + ls;
    // rescale O: alpha indexed by q-row = quad*4+r -> fetch from lane l16=quad*4+r
    #pragma unroll
    for (int r=0;r<4;r++){
      float ar = __shfl(al, quad*4 + r);
      #pragma unroll
      for (int nt=0;nt<8;nt++) o[nt][r] *= ar;
    }
    // P^T (C-layout) -> P A-layout: packed b64 writes then b128 reads (wave-local)
    #pragma unroll
    for (int nt=0;nt<4;nt++){
      unsigned short pk[4];
      #pragma unroll
      for (int r=0;r<4;r++) pk[r] = f2bf(sc[nt][r]);
      *(uint2*)(Pws + l16*80 + nt*16 + quad*4) = *(uint2*)pk;
    }
    ap[0] = *(const short8*)(Pws + l16*80 + quad*8);
    ap[1] = *(const short8*)(Pws + l16*80 + 32 + quad*8);
    // O += P @ V (V already in registers)
    __builtin_amdgcn_s_setprio(1);
    #pragma unroll
    for (int nt=0; nt<8; nt++)
      #pragma unroll
      for (int kc2=0;kc2<2;kc2++)
        o[nt] = __builtin_amdgcn_mfma_f32_16x16x32_bf16(ap[kc2], vf[nt*2+kc2], o[nt], 0,0,0);
    __builtin_amdgcn_s_setprio(0);
  }

  // ---- intra-block combine through LDS ----
  #pragma unroll
  for (int nt=0;nt<8;nt++)
    #pragma unroll
    for (int r=0;r<4;r++)
      Ob[w*2112 + (quad*4 + r)*132 + nt*16 + l16] = o[nt][r];
  if (quad == 0){
    Ml[w][0][l16] = mcol;
    Ml[w][1][l16] = lcol;
  }
  __syncthreads();

  int row = tid >> 4;                  // 0..15
  int c0 = (tid & 15) * 8;             // 8 cols per thread
  float m0_ = fmaxf(fmaxf(Ml[0][0][row], Ml[1][0][row]),
                    fmaxf(Ml[2][0][row], Ml[3][0][row]));
  f32x4 acc0 = (f32x4){0.f,0.f,0.f,0.f};
  f32x4 acc1 = (f32x4){0.f,0.f,0.f,0.f};
  float lsum = 0.f;
  #pragma unroll
  for (int ww=0; ww<4; ww++){
    float e = __expf(Ml[ww][0][row] - m0_);   // empty wave: exp(-1e30-m) = 0
    lsum += Ml[ww][1][row] * e;
    const float* Or = Ob + ww*2112 + row*132 + c0;
    acc0 += *(const f32x4*)(Or)     * e;
    acc1 += *(const f32x4*)(Or + 4) * e;
  }
  float inv = 1.0f / lsum;
  float* op = out + (size_t)(b*2048 + qs + row)*128 + c0;
  acc0 *= inv; acc1 *= inv;
  *(f32x4*)(op)     = acc0;
  *(f32x4*)(op + 4) = acc1;
}

extern "C" void kernel_launch(void* const* d_in, const int* in_sizes, int n_in,
                              void* d_out, int out_size, void* d_ws, size_t ws_size,
                              hipStream_t stream) {
  const float* x  = (const float*)d_in[0];
  const float* Wq = (const float*)d_in[1];
  const float* bq = (const float*)d_in[2];
  const float* Wk = (const float*)d_in[3];
  const float* bk = (const float*)d_in[4];
  const float* Wv = (const float*)d_in[5];
  const float* bv = (const float*)d_in[6];
  char* ws = (char*)d_ws;
  unsigned short* Wt   = (unsigned short*)(ws);             //    786,432 B
  float*          bias = (float*)(ws + 786432);             //      1,536 B
  unsigned short* Qsw  = (unsigned short*)(ws + 788480);    //  2,097,152 B
  unsigned short* Ksw  = (unsigned short*)(ws + 2885632);   //  2,097,152 B
  unsigned short* Vsw  = (unsigned short*)(ws + 4982784);   //  2,097,152 B
  float* out = (float*)d_out;

  hipLaunchKernelGGL(k_prep,    dim3(1536),    dim3(256), 0, stream,
                     Wq, Wk, Wv, bq, bk, bv, Wt, bias);
  hipLaunchKernelGGL(k_gemm_qkv,dim3(384),     dim3(256), 0, stream,
                     x, Wt, bias, Qsw, Ksw, Vsw);
  hipLaunchKernelGGL(k_attn,    dim3(512),     dim3(256), 0, stream,
                     Qsw, Ksw, Vsw, out);
}

// Round 8
// 121.684 us; speedup vs baseline: 1.0351x; 1.0351x over previous
//
#include <hip/hip_runtime.h>
#include <hip/hip_bf16.h>

typedef __attribute__((ext_vector_type(8))) short short8;
typedef __attribute__((ext_vector_type(4))) float f32x4;

static __device__ __forceinline__ unsigned short f2bf(float f){
  union { float f; unsigned int u; } v; v.f = f;
  unsigned int r = v.u + 0x7fffu + ((v.u >> 16) & 1u);
  return (unsigned short)(r >> 16);
}

static __device__ __forceinline__ void load_lds16(const unsigned short* g, unsigned short* l){
  __builtin_amdgcn_global_load_lds(
      (const __attribute__((address_space(1))) unsigned int*)(g),
      (__attribute__((address_space(3))) unsigned int*)(l), 16, 0, 0);
}

// ---------------- kernel 1: fused (x fp32 -> bf16) + (W -> Wt bf16, bias) ------
__global__ void k_prep(const float* __restrict__ x, unsigned short* __restrict__ xb,
                       const float* __restrict__ Wq, const float* __restrict__ Wk,
                       const float* __restrict__ Wv,
                       const float* __restrict__ bq, const float* __restrict__ bk,
                       const float* __restrict__ bv,
                       unsigned short* __restrict__ Wt, float* __restrict__ bias){
  int bx = blockIdx.x;
  int tid = threadIdx.x;
  if (bx < 4096){
    int i = (bx * 256 + tid) * 8;
    float4 a = *(const float4*)(x + i);
    float4 b = *(const float4*)(x + i + 4);
    unsigned short h[8];
    h[0]=f2bf(a.x); h[1]=f2bf(a.y); h[2]=f2bf(a.z); h[3]=f2bf(a.w);
    h[4]=f2bf(b.x); h[5]=f2bf(b.y); h[6]=f2bf(b.z); h[7]=f2bf(b.w);
    *(uint4*)(xb + i) = *(uint4*)h;
  } else {
    int gid = (bx - 4096) * 256 + tid;           // 0 .. 393215
    int p = gid >> 17;
    int rem = gid & 131071;
    int d = rem >> 10, e = rem & 1023;
    const float* W = (p==0) ? Wq : ((p==1) ? Wk : Wv);
    Wt[gid] = f2bf(W[e*128 + d]);                 // Wt[p][d][e] = W[e][d]
    if (gid < 384){
      int pp = gid >> 7, dd = gid & 127;
      bias[gid] = (pp==0) ? bq[dd] : ((pp==1) ? bk[dd] : bv[dd]);
    }
  }
}

// ---------------- kernel 2: QKV GEMM full-K, double-buffered (2-phase),
// fused bias + swizzled bf16 epilogue. 1-D grid 384, XCD-chunked mapping:
// xcd = bid&7 owns 16 consecutive mt x 3 p, with the 3 p-blocks of one mt
// temporally adjacent -> Xb panel re-reads (p=1,2) hit that XCD's L2.
// 64x128 tile, K = 1024 (16 iters of 64). 4 waves. LDS 48 KiB.
//   Qsw/Ksw: [rowtile16][kc(4)][quad(4)][l16(16)][8]
//   Vsw:     [b][t64][nt(8)][kc2(2)][quad(4)][l16(16)][8]
__global__ __launch_bounds__(256) void k_gemm_qkv(
    const unsigned short* __restrict__ Xb, const unsigned short* __restrict__ Wt,
    const float* __restrict__ bias,
    unsigned short* __restrict__ Qsw, unsigned short* __restrict__ Ksw,
    unsigned short* __restrict__ Vsw){
  __shared__ __align__(16) char smem[49152];
  // buffer sel: base = smem + sel*24576; A = base..8K, B = base+8K..24K
  float* Lf = (float*)smem;                              // [64][128] f32 (epilogue)
  int tid = threadIdx.x;
  int bid = blockIdx.x;                // 0..383
  int xcd = bid & 7;
  int slot = bid >> 3;                 // 0..47
  int mtl = slot / 3;
  int p   = slot - mtl*3;              // 0..2
  int mt  = xcd*16 + mtl;              // 0..127
  int m0 = mt * 64;
  int w = tid >> 6, lane = tid & 63, quad = lane >> 4, l16 = lane & 15;
  int wm = (w >> 1) * 32, wn = (w & 1) * 64;
  f32x4 acc[2][4];
  #pragma unroll
  for (int i=0;i<2;i++)
    #pragma unroll
    for (int j=0;j<4;j++) acc[i][j] = (f32x4){0.f,0.f,0.f,0.f};

  const unsigned short* Wp = Wt + p * (128*1024);
  const unsigned short* Ag = Xb + (m0 + w*16 + (lane>>3))*1024 + (lane&7)*8;
  const unsigned short* Bg = Wp + (w*32 + (lane>>3))*1024 + (lane&7)*8;
  int aoff = (w*16)*64;     // shorts; wave-uniform LDS base, HW adds lane*16B
  int boff = (w*32)*64;

  auto stage = [&](int sel, int k0){
    unsigned short* Al = (unsigned short*)(smem + sel*24576) + aoff;
    unsigned short* Bl = (unsigned short*)(smem + sel*24576 + 8192) + boff;
    load_lds16(Ag + k0, Al);
    load_lds16(Ag + k0 + 8192, Al + 512);
    #pragma unroll
    for (int s8=0; s8<4; s8++) load_lds16(Bg + k0 + s8*8192, Bl + s8*512);
  };

  stage(0, 0);
  __syncthreads();                     // tile 0 resident
  int cur = 0;
  for (int t=0; t<16; t++){
    if (t < 15) stage(cur^1, (t+1)*64);     // prefetch next tile during compute
    const unsigned short* Ac = (const unsigned short*)(smem + cur*24576);
    const unsigned short* Bc = Ac + 4096;
    #pragma unroll
    for (int kk=0; kk<64; kk+=32){
      short8 af[2], bf[4];
      #pragma unroll
      for (int i=0;i<2;i++) af[i] = *(const short8*)(Ac + (wm + i*16 + l16)*64 + kk + quad*8);
      #pragma unroll
      for (int j=0;j<4;j++) bf[j] = *(const short8*)(Bc + (wn + j*16 + l16)*64 + kk + quad*8);
      #pragma unroll
      for (int i=0;i<2;i++)
        #pragma unroll
        for (int j=0;j<4;j++)
          acc[i][j] = __builtin_amdgcn_mfma_f32_16x16x32_bf16(af[i], bf[j], acc[i][j], 0,0,0);
    }
    __syncthreads();                   // drains prefetch (vmcnt) + ds_reads of cur
    cur ^= 1;
  }

  const float qscale = 0.08838834764831845f;  // 1/sqrt(128)
  if (p == 2){
    // V: swizzle minor dim (jj) comes from the ROW -> acc's f32x4 axis. Direct store.
    #pragma unroll
    for (int i=0;i<2;i++)
      #pragma unroll
      for (int j=0;j<4;j++){
        int grow0 = m0 + wm + i*16 + quad*4;          // 4-aligned
        int col = wn + j*16 + l16;
        unsigned short pk[4];
        float bv_ = bias[256 + col];
        #pragma unroll
        for (int r=0;r<4;r++) pk[r] = f2bf(acc[i][j][r] + bv_);
        int bb2 = grow0 >> 11, s = grow0 & 2047;
        int t64 = s >> 6, srem = s & 63;
        int kc2 = srem >> 5, q2 = (srem >> 3) & 3, jj = srem & 7;
        int nt = col >> 4, l2 = col & 15;
        *(uint2*)(Vsw + (bb2*32+t64)*8192 + nt*1024 + kc2*512 + q2*128 + l2*8 + jj) = *(uint2*)pk;
      }
  } else {
    // Q/K: need row<->col transpose for the swizzle; roundtrip through LDS.
    #pragma unroll
    for (int i=0;i<2;i++)
      #pragma unroll
      for (int j=0;j<4;j++)
        #pragma unroll
        for (int r=0;r<4;r++)
          Lf[(wm + i*16 + quad*4 + r)*128 + wn + j*16 + l16] = acc[i][j][r];
    __syncthreads();
    unsigned short* dst = (p==0)? Qsw : Ksw;
    float scale = (p==0)? qscale : 1.0f;
    #pragma unroll
    for (int it=0; it<8; it++){
      int g = it*256 + tid;            // 0..2047 (64 rows x 32 col-groups)
      int row = g >> 5, cs = (g & 31)*4;
      f32x4 a = *(const f32x4*)(Lf + row*128 + cs);
      int grow = m0 + row;
      int rt = grow >> 4, m = grow & 15;
      int kc = cs >> 5, q2 = (cs >> 3) & 3, jj = cs & 7;
      unsigned short pk[4];
      #pragma unroll
      for (int k=0;k<4;k++) pk[k] = f2bf((a[k] + bias[p*128+cs+k])*scale);
      *(uint2*)(dst + rt*2048 + kc*512 + q2*128 + m*8 + jj) = *(uint2*)pk;
    }
  }
}

// ---------------- kernel 3: attention, one BLOCK per (b, 16-row q-block) ------
// 4 waves split the kv-tiles; intra-block LDS combine (round-6 validated).
// NEW: load-balance swizzle -- q<64 -> qb=2q, q>=64 -> qb=255-2q, so blocks
// i and i+256 (co-resident pair per CU under round-robin fill) have qb summing
// to 127 -> per-CU work ~= average (9 tile-iters) instead of worst-case 16.
__global__ __launch_bounds__(256) void k_attn(
    const unsigned short* __restrict__ Qsw, const unsigned short* __restrict__ Ksw,
    const unsigned short* __restrict__ Vsw, float* __restrict__ out){
  __shared__ __align__(16) float Ob[4*2112];            // [w][16][132] (pad 132)
  __shared__ float Ml[4][2][16];                        // [w][{m,l}][row]
  __shared__ __align__(16) unsigned short Pw[4*1280];   // per-wave P buffer
  int x = blockIdx.x;                  // 0..511
  int b = x & 3;
  int q = x >> 2;                      // 0..127
  int qb = (q < 64) ? (q*2) : (255 - q*2);   // bijection; complements pair i,i+256
  int T64 = (qb >> 2) + 1;             // 64-key tiles covering keys <= qb*16+15
  int tid = threadIdx.x;
  int w = tid >> 6;
  int lane = tid & 63;
  int quad = lane >> 4, l16 = lane & 15;
  int qs = qb * 16;                    // q rows qs..qs+15; our q col = qs + l16

  short8 aq[4];
  #pragma unroll
  for (int kc=0;kc<4;kc++)
    aq[kc] = *(const short8*)(Qsw + (b*128 + qb)*2048 + kc*512 + lane*8);

  f32x4 o[8];
  #pragma unroll
  for (int i=0;i<8;i++) o[i] = (f32x4){0.f,0.f,0.f,0.f};
  float mcol = -1e30f;
  float lcol = 0.f;
  short8 ap[2];
  unsigned short* Pws = Pw + w*1280;

  const unsigned short* Kb = Ksw + b*128*2048;
  const unsigned short* Vb = Vsw + b*32*8192;

  for (int tt = w; tt < T64; tt += 4){
    int t0 = tt * 64;
    // ---- batch-load ALL 16 K fragments (single exposed latency) ----
    short8 kf[16];
    #pragma unroll
    for (int nt=0;nt<4;nt++){
      const unsigned short* Kt = Kb + ((t0>>4)+nt)*2048 + lane*8;
      #pragma unroll
      for (int kc=0;kc<4;kc++)
        kf[nt*4+kc] = *(const short8*)(Kt + kc*512);
    }
    // S^T = K @ Q^T : A = K frags (m=key), B = Q frags (n=q). C: row=key, col=q.
    f32x4 sc[4];
    #pragma unroll
    for (int nt=0;nt<4;nt++) sc[nt] = (f32x4){0.f,0.f,0.f,0.f};
    __builtin_amdgcn_s_setprio(1);
    #pragma unroll
    for (int nt=0;nt<4;nt++)
      #pragma unroll
      for (int kc=0;kc<4;kc++)
        sc[nt] = __builtin_amdgcn_mfma_f32_16x16x32_bf16(kf[nt*4+kc], aq[kc], sc[nt], 0,0,0);
    __builtin_amdgcn_s_setprio(0);
    // ---- issue ALL 16 V loads now; latency hides under softmax VALU ----
    short8 vf[16];
    const unsigned short* Vt0 = Vb + (t0>>6)*8192 + lane*8;
    #pragma unroll
    for (int nt=0;nt<8;nt++)
      #pragma unroll
      for (int kc2=0;kc2<2;kc2++)
        vf[nt*2+kc2] = *(const short8*)(Vt0 + nt*1024 + kc2*512);

    if (t0 + 63 > qs){                 // mask needed iff tile's max key > min q
      #pragma unroll
      for (int nt=0;nt<4;nt++){
        int kb_ = t0 + nt*16 + quad*4;
        #pragma unroll
        for (int r=0;r<4;r++)
          if (kb_ + r > qs + l16) sc[nt][r] = -1e30f;
      }
    }
    // in-register max over 16 keys, then 2 shuffles across quads
    float mt_ = -1e30f;
    #pragma unroll
    for (int nt=0;nt<4;nt++)
      #pragma unroll
      for (int r=0;r<4;r++) mt_ = fmaxf(mt_, sc[nt][r]);
    mt_ = fmaxf(mt_, __shfl_xor(mt_, 16));
    mt_ = fmaxf(mt_, __shfl_xor(mt_, 32));
    float mn = fmaxf(mcol, mt_);
    float al = __expf(mcol - mn);
    mcol = mn;
    float ls = 0.f;
    #pragma unroll
    for (int nt=0;nt<4;nt++)
      #pragma unroll
      for (int r=0;r<4;r++){
        float pv = __expf(sc[nt][r] - mn);
        sc[nt][r] = pv;
        ls += pv;
      }
    ls += __shfl_xor(ls, 16);
    ls += __shfl_xor(ls, 32);
    lcol = lcol*al + ls;
    // rescale O: alpha indexed by q-row = quad*4+r -> fetch from lane l16=quad*4+r
    #pragma unroll
    for (int r=0;r<4;r++){
      float ar = __shfl(al, quad*4 + r);
      #pragma unroll
      for (int nt=0;nt<8;nt++) o[nt][r] *= ar;
    }
    // P^T (C-layout) -> P A-layout: packed b64 writes then b128 reads (wave-local)
    #pragma unroll
    for (int nt=0;nt<4;nt++){
      unsigned short pk[4];
      #pragma unroll
      for (int r=0;r<4;r++) pk[r] = f2bf(sc[nt][r]);
      *(uint2*)(Pws + l16*80 + nt*16 + quad*4) = *(uint2*)pk;
    }
    ap[0] = *(const short8*)(Pws + l16*80 + quad*8);
    ap[1] = *(const short8*)(Pws + l16*80 + 32 + quad*8);
    // O += P @ V (V already in registers)
    __builtin_amdgcn_s_setprio(1);
    #pragma unroll
    for (int nt=0; nt<8; nt++)
      #pragma unroll
      for (int kc2=0;kc2<2;kc2++)
        o[nt] = __builtin_amdgcn_mfma_f32_16x16x32_bf16(ap[kc2], vf[nt*2+kc2], o[nt], 0,0,0);
    __builtin_amdgcn_s_setprio(0);
  }

  // ---- intra-block combine through LDS ----
  #pragma unroll
  for (int nt=0;nt<8;nt++)
    #pragma unroll
    for (int r=0;r<4;r++)
      Ob[w*2112 + (quad*4 + r)*132 + nt*16 + l16] = o[nt][r];
  if (quad == 0){
    Ml[w][0][l16] = mcol;
    Ml[w][1][l16] = lcol;
  }
  __syncthreads();

  int row = tid >> 4;                  // 0..15
  int c0 = (tid & 15) * 8;             // 8 cols per thread
  float m0_ = fmaxf(fmaxf(Ml[0][0][row], Ml[1][0][row]),
                    fmaxf(Ml[2][0][row], Ml[3][0][row]));
  f32x4 acc0 = (f32x4){0.f,0.f,0.f,0.f};
  f32x4 acc1 = (f32x4){0.f,0.f,0.f,0.f};
  float lsum = 0.f;
  #pragma unroll
  for (int ww=0; ww<4; ww++){
    float e = __expf(Ml[ww][0][row] - m0_);   // empty wave: exp(-1e30-m) = 0
    lsum += Ml[ww][1][row] * e;
    const float* Or = Ob + ww*2112 + row*132 + c0;
    acc0 += *(const f32x4*)(Or)     * e;
    acc1 += *(const f32x4*)(Or + 4) * e;
  }
  float inv = 1.0f / lsum;
  float* op = out + (size_t)(b*2048 + qs + row)*128 + c0;
  acc0 *= inv; acc1 *= inv;
  *(f32x4*)(op)     = acc0;
  *(f32x4*)(op + 4) = acc1;
}

extern "C" void kernel_launch(void* const* d_in, const int* in_sizes, int n_in,
                              void* d_out, int out_size, void* d_ws, size_t ws_size,
                              hipStream_t stream) {
  const float* x  = (const float*)d_in[0];
  const float* Wq = (const float*)d_in[1];
  const float* bq = (const float*)d_in[2];
  const float* Wk = (const float*)d_in[3];
  const float* bk = (const float*)d_in[4];
  const float* Wv = (const float*)d_in[5];
  const float* bv = (const float*)d_in[6];
  char* ws = (char*)d_ws;
  unsigned short* Xb   = (unsigned short*)(ws);             // 16,777,216 B
  unsigned short* Wt   = (unsigned short*)(ws + 16777216);  //    786,432 B
  float*          bias = (float*)(ws + 17563648);           //      1,536 B
  unsigned short* Qsw  = (unsigned short*)(ws + 17565184);  //  2,097,152 B
  unsigned short* Ksw  = (unsigned short*)(ws + 19662336);  //  2,097,152 B
  unsigned short* Vsw  = (unsigned short*)(ws + 21759488);  //  2,097,152 B
  float* out = (float*)d_out;

  hipLaunchKernelGGL(k_prep,    dim3(5632),    dim3(256), 0, stream,
                     x, Xb, Wq, Wk, Wv, bq, bk, bv, Wt, bias);
  hipLaunchKernelGGL(k_gemm_qkv,dim3(384),     dim3(256), 0, stream,
                     Xb, Wt, bias, Qsw, Ksw, Vsw);
  hipLaunchKernelGGL(k_attn,    dim3(512),     dim3(256), 0, stream,
                     Qsw, Ksw, Vsw, out);
}